// Round 3
// baseline (470.374 us; speedup 1.0000x reference)
//
#include <hip/hip_runtime.h>

#define N_NODES 100000
#define N_EDGES 1000000
#define D 64
#define NCLS 10

#define SCAN_BLOCK 256
#define N_SCAN_BLOCKS ((N_NODES + SCAN_BLOCK - 1) / SCAN_BLOCK)  // 391

#define NPW 8                 // nodes per wave in fused sage kernel
#define WAVES 8               // waves per block (512 threads)
#define NPB (NPW * WAVES)     // 64 nodes per block

// round-to-nearest-even f32 -> bf16 bits
__device__ __forceinline__ unsigned short f2bf(float x) {
    unsigned int u = __float_as_uint(x);
    u += 0x7fffu + ((u >> 16) & 1u);
    return (unsigned short)(u >> 16);
}

// ---------------------------------------------------------------------------
// CSR build step 1: in-degree counts (int atomics; same graph both layers)
// ---------------------------------------------------------------------------
__global__ __launch_bounds__(256) void count_edges(const int* __restrict__ dst,
                                                   int* __restrict__ cnt) {
    int e = blockIdx.x * blockDim.x + threadIdx.x;
    if (e < N_EDGES) atomicAdd(&cnt[dst[e]], 1);
}

// CSR step 2a: per-block sums of counts
__global__ __launch_bounds__(256) void scan_partials(const int* __restrict__ cnt,
                                                     int* __restrict__ blockSum) {
    __shared__ int s[256];
    int i = blockIdx.x * 256 + threadIdx.x;
    s[threadIdx.x] = (i < N_NODES) ? cnt[i] : 0;
    __syncthreads();
    for (int st = 128; st > 0; st >>= 1) {
        if (threadIdx.x < st) s[threadIdx.x] += s[threadIdx.x + st];
        __syncthreads();
    }
    if (threadIdx.x == 0) blockSum[blockIdx.x] = s[0];
}

// CSR step 2b: exclusive scan of the 391 block sums (single block)
__global__ __launch_bounds__(512) void scan_offsets(const int* __restrict__ blockSum,
                                                    int* __restrict__ blockOff) {
    __shared__ int s[512];
    int t = threadIdx.x;
    int v = (t < N_SCAN_BLOCKS) ? blockSum[t] : 0;
    s[t] = v;
    __syncthreads();
    for (int st = 1; st < 512; st <<= 1) {
        int u = (t >= st) ? s[t - st] : 0;
        __syncthreads();
        s[t] += u;
        __syncthreads();
    }
    if (t < N_SCAN_BLOCKS) blockOff[t] = s[t] - v;  // exclusive
}

// CSR step 2c: per-element exclusive scan -> row_ptr, cursor
__global__ __launch_bounds__(256) void scan_final(const int* __restrict__ cnt,
                                                  const int* __restrict__ blockOff,
                                                  int* __restrict__ row_ptr,
                                                  int* __restrict__ cursor) {
    __shared__ int s[256];
    int i = blockIdx.x * 256 + threadIdx.x;
    int t = threadIdx.x;
    int v = (i < N_NODES) ? cnt[i] : 0;
    s[t] = v;
    __syncthreads();
    for (int st = 1; st < 256; st <<= 1) {
        int u = (t >= st) ? s[t - st] : 0;
        __syncthreads();
        s[t] += u;
        __syncthreads();
    }
    int excl = s[t] - v + blockOff[blockIdx.x];
    if (i < N_NODES) { row_ptr[i] = excl; cursor[i] = excl; }
    if (i == 0) row_ptr[N_NODES] = N_EDGES;
}

// CSR step 3: permute edge sources into dst-sorted order
__global__ __launch_bounds__(256) void fill_csr(const int* __restrict__ src,
                                                const int* __restrict__ dst,
                                                int* __restrict__ cursor,
                                                int* __restrict__ sorted_src) {
    int e = blockIdx.x * blockDim.x + threadIdx.x;
    if (e < N_EDGES) {
        int p = atomicAdd(&cursor[dst[e]], 1);
        sorted_src[p] = src[e];
    }
}

// ---------------------------------------------------------------------------
// fp32 -> packed bf16 feature table (row = 64 ushorts = 32 dwords = 128B)
// ---------------------------------------------------------------------------
__global__ __launch_bounds__(256) void to_bf16(const float* __restrict__ in,
                                               unsigned short* __restrict__ out) {
    int i = blockIdx.x * 256 + threadIdx.x;   // float4 index
    if (i < N_NODES * D / 4) {
        float4 v = ((const float4*)in)[i];
        ushort4 o;
        o.x = f2bf(v.x); o.y = f2bf(v.y); o.z = f2bf(v.z); o.w = f2bf(v.w);
        ((ushort4*)out)[i] = o;
    }
}

// ---------------------------------------------------------------------------
// Fused SAGE layer: out = relu(mean_{CSR} @ Wl^T + x @ Wr^T + b)
// Gather phase: wave per node, bf16 rows (128B) -> 2 edges per load
//   (lanes 0-31 = edge i, lanes 32-63 = edge i+1; each lane owns a packed
//    feature pair; halves merged by one shfl_xor(32) per node).
// Self path + weights + GEMV stay fp32. Weights LDS chunk-XOR-swizzled so
// lane f reads its own row conflict-free via ds_read_b128.
// ---------------------------------------------------------------------------
__global__ __launch_bounds__(512) void sage_fused(
        const float* __restrict__ self_feat,       // fp32 [N][64]
        const unsigned int* __restrict__ featb,    // bf16-packed [N][32]
        const int* __restrict__ row_ptr,
        const int* __restrict__ sorted_src,
        const float* __restrict__ Wl,
        const float* __restrict__ Wr,
        const float* __restrict__ bias,
        float* __restrict__ out,                   // fp32 [N][64]
        unsigned short* __restrict__ outb) {       // optional bf16 copy
    __shared__ __align__(16) float sWl[D * D];
    __shared__ __align__(16) float sWr[D * D];
    __shared__ __align__(16) float srow[WAVES][NPW][2][D];  // [wave][node][self/mean][k]

    // stage weights (swizzled), float4 in and out
    for (int i = threadIdx.x; i < D * D / 4; i += 512) {
        int o = i >> 4;          // row
        int c = i & 15;          // logical chunk (4 floats)
        int pc = c ^ (o & 15);   // physical chunk
        *((float4*)&sWl[(o << 6) + (pc << 2)]) = ((const float4*)Wl)[i];
        *((float4*)&sWr[(o << 6) + (pc << 2)]) = ((const float4*)Wr)[i];
    }
    __syncthreads();

    const int w  = threadIdx.x >> 6;   // wave id
    const int f  = threadIdx.x & 63;   // lane
    const int h  = f >> 5;             // half id (edge parity)
    const int l5 = f & 31;             // dword within row (features 2*l5, 2*l5+1)
    const int nodeBase = blockIdx.x * NPB + w * NPW;
    const float bl = bias[f];

    // ---- gather phase: mean + self rows for NPW nodes (wave-private) ----
    for (int r = 0; r < NPW; ++r) {
        int node = nodeBase + r;
        if (node >= N_NODES) break;
        int start = row_ptr[node];
        int deg   = row_ptr[node + 1] - start;

        float a0 = 0.f, a1 = 0.f, a2 = 0.f, a3 = 0.f;
        for (int base = 0; base < deg; base += 64) {
            int nb = min(64, deg - base);
            int sl = (f < nb) ? sorted_src[start + base + f] : 0;
            int npairs = (nb + 1) >> 1;
            int t = 0;
            for (; t + 2 <= npairs; t += 2) {           // 4 edges / iter, 2 loads in flight
                int iA = 2 * t + h;
                int iB = 2 * t + 2 + h;
                int sA = __shfl(sl, iA);
                int sB = __shfl(sl, iB);
                unsigned int wA = (iA < nb) ? featb[sA * 32 + l5] : 0u;
                unsigned int wB = (iB < nb) ? featb[sB * 32 + l5] : 0u;
                a0 += __uint_as_float(wA << 16);
                a1 += __uint_as_float(wA & 0xffff0000u);
                a2 += __uint_as_float(wB << 16);
                a3 += __uint_as_float(wB & 0xffff0000u);
            }
            if (t < npairs) {                           // tail pair (<= 2 edges)
                int iA = 2 * t + h;
                int sA = __shfl(sl, iA);
                unsigned int wA = (iA < nb) ? featb[sA * 32 + l5] : 0u;
                a0 += __uint_as_float(wA << 16);
                a1 += __uint_as_float(wA & 0xffff0000u);
            }
        }
        float b0 = a0 + a2;
        float b1 = a1 + a3;
        b0 += __shfl_xor(b0, 32);   // combine the two edge-parity halves
        b1 += __shfl_xor(b1, 32);
        float inv = 1.0f / fmaxf((float)deg, 1.0f);

        srow[w][r][0][f] = self_feat[node * D + f];     // self row, fp32
        if (h == 0) {
            srow[w][r][1][2 * l5]     = b0 * inv;       // mean row
            srow[w][r][1][2 * l5 + 1] = b1 * inv;
        }
    }
    // srow written and read by the same wave -> no block barrier needed

    // ---- GEMV phase: 8 nodes share each weight read ----
    float acc[NPW];
#pragma unroll
    for (int r = 0; r < NPW; ++r) acc[r] = bl;

#pragma unroll 4
    for (int c = 0; c < 16; ++c) {
        const int wi = (f << 6) + ((c ^ (f & 15)) << 2);
        const float4 wl4 = *(const float4*)&sWl[wi];
        const float4 wr4 = *(const float4*)&sWr[wi];
#pragma unroll
        for (int r = 0; r < NPW; ++r) {
            const float4 m4 = *(const float4*)&srow[w][r][1][c << 2];
            const float4 s4 = *(const float4*)&srow[w][r][0][c << 2];
            float a = acc[r];
            a = fmaf(m4.x, wl4.x, a); a = fmaf(m4.y, wl4.y, a);
            a = fmaf(m4.z, wl4.z, a); a = fmaf(m4.w, wl4.w, a);
            a = fmaf(s4.x, wr4.x, a); a = fmaf(s4.y, wr4.y, a);
            a = fmaf(s4.z, wr4.z, a); a = fmaf(s4.w, wr4.w, a);
            acc[r] = a;
        }
    }

#pragma unroll
    for (int r = 0; r < NPW; ++r) {
        int node = nodeBase + r;
        if (node < N_NODES) {
            float v = fmaxf(acc[r], 0.0f);  // both sage layers are relu'd
            out[node * D + f] = v;
            if (outb) outb[node * D + f] = f2bf(v);
        }
    }
}

// ---------------------------------------------------------------------------
// Output projection: out = h @ W_out^T + b_out   [N, 10]
// ---------------------------------------------------------------------------
__global__ __launch_bounds__(256) void out_layer(const float* __restrict__ h,
                                                 const float* __restrict__ Wout,
                                                 const float* __restrict__ bout,
                                                 float* __restrict__ out) {
    __shared__ float sW[NCLS][D + 1];
    __shared__ float sh[64][D + 1];

    for (int i = threadIdx.x; i < NCLS * D; i += 256) {
        sW[i / D][i % D] = Wout[i];
    }
    int n0 = blockIdx.x * 64;
    for (int i = threadIdx.x; i < 64 * D; i += 256) {
        int nl = i >> 6, k = i & 63;
        int node = n0 + nl;
        sh[nl][k] = (node < N_NODES) ? h[(long long)node * D + k] : 0.0f;
    }
    __syncthreads();

    for (int oi = threadIdx.x; oi < 64 * NCLS; oi += 256) {
        int nl = oi / NCLS, c = oi % NCLS;
        int node = n0 + nl;
        if (node >= N_NODES) continue;
        float acc = bout[c];
#pragma unroll
        for (int k = 0; k < D; ++k) acc = fmaf(sh[nl][k], sW[c][k], acc);
        out[(long long)node * NCLS + c] = acc;
    }
}

// ---------------------------------------------------------------------------
extern "C" void kernel_launch(void* const* d_in, const int* in_sizes, int n_in,
                              void* d_out, int out_size, void* d_ws, size_t ws_size,
                              hipStream_t stream) {
    const float* x   = (const float*)d_in[0];
    const int*   ei  = (const int*)d_in[1];   // [2, N_EDGES]
    const int*   src = ei;
    const int*   dst = ei + N_EDGES;
    const float* W1l = (const float*)d_in[2];
    const float* W1r = (const float*)d_in[3];
    const float* b1  = (const float*)d_in[4];
    const float* W2l = (const float*)d_in[5];
    const float* W2r = (const float*)d_in[6];
    const float* b2  = (const float*)d_in[7];
    const float* Wo  = (const float*)d_in[8];
    const float* bo  = (const float*)d_in[9];
    float* out = (float*)d_out;

    char* ws = (char*)d_ws;
    int*   cnt        = (int*)(ws + 0x000000);   // 400 KB
    int*   row_ptr    = (int*)(ws + 0x068000);   // 400 KB + 4
    int*   cursor     = (int*)(ws + 0x0D0000);   // 400 KB
    int*   blockSum   = (int*)(ws + 0x138000);   // 2 KB
    int*   blockOff   = (int*)(ws + 0x13A000);   // 2 KB
    int*   sorted_src = (int*)(ws + 0x140000);   // 4 MB
    float*          h1  = (float*)(ws + 0x540000);            // 25.6 MB fp32
    unsigned short* h1b = (unsigned short*)(ws + 0x1DB0000);  // 12.8 MB bf16
    unsigned short* xb  = (unsigned short*)(ws + 0x29F0000);  // 12.8 MB bf16
    float*          h2  = (float*)(ws + 0x29F0000);           // 25.6 MB, aliases xb (xb dead
                                                              // after layer-1 sage)

    const int edge_blocks = (N_EDGES + 255) / 256;     // 3907
    const int sage_blocks = (N_NODES + NPB - 1) / NPB; // 1563
    const int out_blocks  = (N_NODES + 63) / 64;       // 1563
    const int cvt_blocks  = (N_NODES * D / 4 + 255) / 256;

    // ---- CSR build (once; shared by both layers) ----
    hipMemsetAsync(cnt, 0, N_NODES * sizeof(int), stream);
    count_edges<<<edge_blocks, 256, 0, stream>>>(dst, cnt);
    scan_partials<<<N_SCAN_BLOCKS, 256, 0, stream>>>(cnt, blockSum);
    scan_offsets<<<1, 512, 0, stream>>>(blockSum, blockOff);
    scan_final<<<N_SCAN_BLOCKS, 256, 0, stream>>>(cnt, blockOff, row_ptr, cursor);
    fill_csr<<<edge_blocks, 256, 0, stream>>>(src, dst, cursor, sorted_src);

    // ---- bf16 gather table for layer 1 ----
    to_bf16<<<cvt_blocks, 256, 0, stream>>>(x, xb);

    // ---- layers ----
    sage_fused<<<sage_blocks, 512, 0, stream>>>(x, (const unsigned int*)xb,
                                                row_ptr, sorted_src,
                                                W1l, W1r, b1, h1, h1b);
    sage_fused<<<sage_blocks, 512, 0, stream>>>(h1, (const unsigned int*)h1b,
                                                row_ptr, sorted_src,
                                                W2l, W2r, b2, h2, (unsigned short*)0);
    out_layer<<<out_blocks, 256, 0, stream>>>(h2, Wo, bo, out);
}

// Round 4
// 317.552 us; speedup vs baseline: 1.4812x; 1.4812x over previous
//
#include <hip/hip_runtime.h>

#define N_NODES 100000
#define N_EDGES 1000000
#define D 64
#define NCLS 10

#define SCAN_BLOCK 256
#define N_SCAN_BLOCKS ((N_NODES + SCAN_BLOCK - 1) / SCAN_BLOCK)  // 391

#define NPW 8                 // nodes per wave in GEMV kernel
#define GEMV_WAVES 4
#define GEMV_NPB (NPW * GEMV_WAVES)   // 32 nodes per 256-thread block

// round-to-nearest-even f32 -> bf16 bits
__device__ __forceinline__ unsigned short f2bf(float x) {
    unsigned int u = __float_as_uint(x);
    u += 0x7fffu + ((u >> 16) & 1u);
    return (unsigned short)(u >> 16);
}
__device__ __forceinline__ unsigned int pack2bf(float lo, float hi) {
    return (unsigned int)f2bf(lo) | ((unsigned int)f2bf(hi) << 16);
}

// ---------------------------------------------------------------------------
// CSR build step 1: in-degree counts (int atomics; same graph both layers)
// ---------------------------------------------------------------------------
__global__ __launch_bounds__(256) void count_edges(const int* __restrict__ dst,
                                                   int* __restrict__ cnt) {
    int e = blockIdx.x * blockDim.x + threadIdx.x;
    if (e < N_EDGES) atomicAdd(&cnt[dst[e]], 1);
}

// CSR step 2a: per-block sums of counts
__global__ __launch_bounds__(256) void scan_partials(const int* __restrict__ cnt,
                                                     int* __restrict__ blockSum) {
    __shared__ int s[256];
    int i = blockIdx.x * 256 + threadIdx.x;
    s[threadIdx.x] = (i < N_NODES) ? cnt[i] : 0;
    __syncthreads();
    for (int st = 128; st > 0; st >>= 1) {
        if (threadIdx.x < st) s[threadIdx.x] += s[threadIdx.x + st];
        __syncthreads();
    }
    if (threadIdx.x == 0) blockSum[blockIdx.x] = s[0];
}

// CSR step 2b: exclusive scan of the 391 block sums (single block)
__global__ __launch_bounds__(512) void scan_offsets(const int* __restrict__ blockSum,
                                                    int* __restrict__ blockOff) {
    __shared__ int s[512];
    int t = threadIdx.x;
    int v = (t < N_SCAN_BLOCKS) ? blockSum[t] : 0;
    s[t] = v;
    __syncthreads();
    for (int st = 1; st < 512; st <<= 1) {
        int u = (t >= st) ? s[t - st] : 0;
        __syncthreads();
        s[t] += u;
        __syncthreads();
    }
    if (t < N_SCAN_BLOCKS) blockOff[t] = s[t] - v;  // exclusive
}

// CSR step 2c: per-element exclusive scan -> row_ptr, cursor
__global__ __launch_bounds__(256) void scan_final(const int* __restrict__ cnt,
                                                  const int* __restrict__ blockOff,
                                                  int* __restrict__ row_ptr,
                                                  int* __restrict__ cursor) {
    __shared__ int s[256];
    int i = blockIdx.x * 256 + threadIdx.x;
    int t = threadIdx.x;
    int v = (i < N_NODES) ? cnt[i] : 0;
    s[t] = v;
    __syncthreads();
    for (int st = 1; st < 256; st <<= 1) {
        int u = (t >= st) ? s[t - st] : 0;
        __syncthreads();
        s[t] += u;
        __syncthreads();
    }
    int excl = s[t] - v + blockOff[blockIdx.x];
    if (i < N_NODES) { row_ptr[i] = excl; cursor[i] = excl; }
    if (i == 0) row_ptr[N_NODES] = N_EDGES;
}

// CSR step 3: permute edge sources into dst-sorted order
__global__ __launch_bounds__(256) void fill_csr(const int* __restrict__ src,
                                                const int* __restrict__ dst,
                                                int* __restrict__ cursor,
                                                int* __restrict__ sorted_src) {
    int e = blockIdx.x * blockDim.x + threadIdx.x;
    if (e < N_EDGES) {
        int p = atomicAdd(&cursor[dst[e]], 1);
        sorted_src[p] = src[e];
    }
}

// ---------------------------------------------------------------------------
// fp32 -> packed bf16 feature table (row = 64 ushorts = 32 dwords = 128B)
// ---------------------------------------------------------------------------
__global__ __launch_bounds__(256) void to_bf16(const float* __restrict__ in,
                                               unsigned short* __restrict__ out) {
    int i = blockIdx.x * 256 + threadIdx.x;   // float4 index
    if (i < N_NODES * D / 4) {
        float4 v = ((const float4*)in)[i];
        ushort4 o;
        o.x = f2bf(v.x); o.y = f2bf(v.y); o.z = f2bf(v.z); o.w = f2bf(v.w);
        ((ushort4*)out)[i] = o;
    }
}

// ---------------------------------------------------------------------------
// Gather kernel: mean over CSR neighbors, bf16 rows -> bf16 mean rows.
// ZERO LDS, small VGPR footprint -> max occupancy; this phase is purely
// latency-bound so waves-in-flight is the lever.
// One wave per node. bf16 row = 128B = 32 dwords: lanes 0-31 carry edge i,
// lanes 32-63 edge i+1 (h = edge parity). 4 loads (8 edges) in flight.
// ---------------------------------------------------------------------------
__global__ __launch_bounds__(256) void gather_mean(
        const unsigned int* __restrict__ featb,   // bf16-packed [N][32]
        const int* __restrict__ row_ptr,
        const int* __restrict__ sorted_src,
        unsigned int* __restrict__ meanb) {       // bf16-packed [N][32]
    const int w  = threadIdx.x >> 6;
    const int f  = threadIdx.x & 63;
    const int h  = f >> 5;             // edge parity
    const int l5 = f & 31;             // dword within row
    const int node = blockIdx.x * 4 + w;
    if (node >= N_NODES) return;

    int start = row_ptr[node];
    int deg   = row_ptr[node + 1] - start;

    float a0 = 0.f, a1 = 0.f, a2 = 0.f, a3 = 0.f,
          a4 = 0.f, a5 = 0.f, a6 = 0.f, a7 = 0.f;
    for (int base = 0; base < deg; base += 64) {
        int nb = min(64, deg - base);
        int sl = (f < nb) ? sorted_src[start + base + f] : 0;
        int npairs = (nb + 1) >> 1;
        int t = 0;
        for (; t + 4 <= npairs; t += 4) {          // 8 edges, 4 loads in flight
            int iA = 2 * t + h, iB = iA + 2, iC = iA + 4, iD = iA + 6;
            int sA = __shfl(sl, iA), sB = __shfl(sl, iB);
            int sC = __shfl(sl, iC), sD = __shfl(sl, iD);
            unsigned int wA = (iA < nb) ? featb[sA * 32 + l5] : 0u;
            unsigned int wB = (iB < nb) ? featb[sB * 32 + l5] : 0u;
            unsigned int wC = (iC < nb) ? featb[sC * 32 + l5] : 0u;
            unsigned int wD = (iD < nb) ? featb[sD * 32 + l5] : 0u;
            a0 += __uint_as_float(wA << 16);
            a1 += __uint_as_float(wA & 0xffff0000u);
            a2 += __uint_as_float(wB << 16);
            a3 += __uint_as_float(wB & 0xffff0000u);
            a4 += __uint_as_float(wC << 16);
            a5 += __uint_as_float(wC & 0xffff0000u);
            a6 += __uint_as_float(wD << 16);
            a7 += __uint_as_float(wD & 0xffff0000u);
        }
        for (; t < npairs; ++t) {                  // tail pairs
            int iA = 2 * t + h;
            int sA = __shfl(sl, iA);
            unsigned int wA = (iA < nb) ? featb[sA * 32 + l5] : 0u;
            a0 += __uint_as_float(wA << 16);
            a1 += __uint_as_float(wA & 0xffff0000u);
        }
    }
    float b0 = (a0 + a2) + (a4 + a6);   // feature 2*l5
    float b1 = (a1 + a3) + (a5 + a7);   // feature 2*l5+1
    b0 += __shfl_xor(b0, 32);           // combine edge-parity halves
    b1 += __shfl_xor(b1, 32);
    float inv = 1.0f / fmaxf((float)deg, 1.0f);
    if (h == 0) meanb[node * 32 + l5] = pack2bf(b0 * inv, b1 * inv);
}

// ---------------------------------------------------------------------------
// Streaming fused GEMV: out = relu(mean @ Wl^T + self @ Wr^T + b)
// Weights in chunk-XOR-swizzled LDS (conflict-free ds_read_b128); each wave
// amortizes a weight read over 8 nodes. Purely streaming I/O, BW-bound.
// out fp32 + optional bf16 copy; outb32 variant writes ONLY bf16 (layer 2).
// ---------------------------------------------------------------------------
__global__ __launch_bounds__(256) void sage_gemv(
        const float* __restrict__ self_feat,       // fp32 [N][64]
        const unsigned int* __restrict__ meanb,    // bf16-packed [N][32]
        const float* __restrict__ Wl,
        const float* __restrict__ Wr,
        const float* __restrict__ bias,
        float* __restrict__ out,                   // fp32 [N][64] (may be null)
        unsigned short* __restrict__ outb) {       // bf16 [N][64] (may be null)
    __shared__ __align__(16) float sWl[D * D];
    __shared__ __align__(16) float sWr[D * D];
    __shared__ __align__(16) float srow[GEMV_WAVES][NPW][2][D];

    for (int i = threadIdx.x; i < D * D / 4; i += 256) {
        int o = i >> 4;          // row
        int c = i & 15;          // logical chunk (4 floats)
        int pc = c ^ (o & 15);   // physical chunk
        *((float4*)&sWl[(o << 6) + (pc << 2)]) = ((const float4*)Wl)[i];
        *((float4*)&sWr[(o << 6) + (pc << 2)]) = ((const float4*)Wr)[i];
    }
    __syncthreads();

    const int w = threadIdx.x >> 6;
    const int f = threadIdx.x & 63;
    const int nodeBase = blockIdx.x * GEMV_NPB + w * NPW;
    const float bl = bias[f];

    // stage 8 nodes' self+mean rows (wave-private -> no block barrier)
#pragma unroll
    for (int r = 0; r < NPW; ++r) {
        int node = nodeBase + r;
        if (node >= N_NODES) break;
        srow[w][r][0][f] = self_feat[node * D + f];
        unsigned int mw = meanb[node * 32 + (f >> 1)];
        srow[w][r][1][f] = __uint_as_float((f & 1) ? (mw & 0xffff0000u) : (mw << 16));
    }

    float acc[NPW];
#pragma unroll
    for (int r = 0; r < NPW; ++r) acc[r] = bl;

#pragma unroll 4
    for (int c = 0; c < 16; ++c) {
        const int wi = (f << 6) + ((c ^ (f & 15)) << 2);
        const float4 wl4 = *(const float4*)&sWl[wi];
        const float4 wr4 = *(const float4*)&sWr[wi];
#pragma unroll
        for (int r = 0; r < NPW; ++r) {
            const float4 m4 = *(const float4*)&srow[w][r][1][c << 2];
            const float4 s4 = *(const float4*)&srow[w][r][0][c << 2];
            float a = acc[r];
            a = fmaf(m4.x, wl4.x, a); a = fmaf(m4.y, wl4.y, a);
            a = fmaf(m4.z, wl4.z, a); a = fmaf(m4.w, wl4.w, a);
            a = fmaf(s4.x, wr4.x, a); a = fmaf(s4.y, wr4.y, a);
            a = fmaf(s4.z, wr4.z, a); a = fmaf(s4.w, wr4.w, a);
            acc[r] = a;
        }
    }

#pragma unroll
    for (int r = 0; r < NPW; ++r) {
        int node = nodeBase + r;
        if (node < N_NODES) {
            float v = fmaxf(acc[r], 0.0f);
            if (out)  out[node * D + f] = v;
            if (outb) outb[node * D + f] = f2bf(v);
        }
    }
}

// ---------------------------------------------------------------------------
// Output projection from bf16 h2: out = h @ W_out^T + b_out   [N, 10]
// ---------------------------------------------------------------------------
__global__ __launch_bounds__(256) void out_layer(const unsigned int* __restrict__ hb,
                                                 const float* __restrict__ Wout,
                                                 const float* __restrict__ bout,
                                                 float* __restrict__ out) {
    __shared__ float sW[NCLS][D + 1];
    __shared__ float sh[64][D + 1];

    for (int i = threadIdx.x; i < NCLS * D; i += 256) {
        sW[i / D][i % D] = Wout[i];
    }
    int n0 = blockIdx.x * 64;
    for (int i = threadIdx.x; i < 64 * 32; i += 256) {   // bf16 words
        int nl = i >> 5, kw = i & 31;
        int node = n0 + nl;
        unsigned int v = (node < N_NODES) ? hb[node * 32 + kw] : 0u;
        sh[nl][2 * kw]     = __uint_as_float(v << 16);
        sh[nl][2 * kw + 1] = __uint_as_float(v & 0xffff0000u);
    }
    __syncthreads();

    for (int oi = threadIdx.x; oi < 64 * NCLS; oi += 256) {
        int nl = oi / NCLS, c = oi % NCLS;
        int node = n0 + nl;
        if (node >= N_NODES) continue;
        float acc = bout[c];
#pragma unroll
        for (int k = 0; k < D; ++k) acc = fmaf(sh[nl][k], sW[c][k], acc);
        out[(long long)node * NCLS + c] = acc;
    }
}

// ---------------------------------------------------------------------------
extern "C" void kernel_launch(void* const* d_in, const int* in_sizes, int n_in,
                              void* d_out, int out_size, void* d_ws, size_t ws_size,
                              hipStream_t stream) {
    const float* x   = (const float*)d_in[0];
    const int*   ei  = (const int*)d_in[1];   // [2, N_EDGES]
    const int*   src = ei;
    const int*   dst = ei + N_EDGES;
    const float* W1l = (const float*)d_in[2];
    const float* W1r = (const float*)d_in[3];
    const float* b1  = (const float*)d_in[4];
    const float* W2l = (const float*)d_in[5];
    const float* W2r = (const float*)d_in[6];
    const float* b2  = (const float*)d_in[7];
    const float* Wo  = (const float*)d_in[8];
    const float* bo  = (const float*)d_in[9];
    float* out = (float*)d_out;

    char* ws = (char*)d_ws;
    int*   cnt        = (int*)(ws + 0x0000000);  // 400 KB
    int*   row_ptr    = (int*)(ws + 0x0068000);  // 400 KB + 4
    int*   cursor     = (int*)(ws + 0x00D0000);  // 400 KB
    int*   blockSum   = (int*)(ws + 0x0138000);  // 2 KB
    int*   blockOff   = (int*)(ws + 0x013A000);  // 2 KB
    int*   sorted_src = (int*)(ws + 0x0140000);  // 4 MB      -> ends 0x540000
    unsigned short* xb    = (unsigned short*)(ws + 0x0540000); // 12.8 MB bf16
    unsigned short* h2b   = (unsigned short*)(ws + 0x0540000); // aliases xb (dead after gather1)
    unsigned int*   meanb = (unsigned int*)(ws + 0x1180000);   // 12.8 MB bf16
    float*          h1    = (float*)(ws + 0x1DC0000);          // 25.6 MB fp32
    unsigned short* h1b   = (unsigned short*)(ws + 0x3630000); // 12.8 MB bf16
    // total ws use: 0x3630000 + 0xC35000 = ~70.6 MB (same envelope as prior rounds)

    const int edge_blocks   = (N_EDGES + 255) / 256;              // 3907
    const int gather_blocks = (N_NODES + 3) / 4;                  // 25000
    const int gemv_blocks   = (N_NODES + GEMV_NPB - 1) / GEMV_NPB;// 3125
    const int out_blocks    = (N_NODES + 63) / 64;                // 1563
    const int cvt_blocks    = (N_NODES * D / 4 + 255) / 256;

    // ---- CSR build (once; shared by both layers) ----
    hipMemsetAsync(cnt, 0, N_NODES * sizeof(int), stream);
    count_edges<<<edge_blocks, 256, 0, stream>>>(dst, cnt);
    scan_partials<<<N_SCAN_BLOCKS, 256, 0, stream>>>(cnt, blockSum);
    scan_offsets<<<1, 512, 0, stream>>>(blockSum, blockOff);
    scan_final<<<N_SCAN_BLOCKS, 256, 0, stream>>>(cnt, blockOff, row_ptr, cursor);
    fill_csr<<<edge_blocks, 256, 0, stream>>>(src, dst, cursor, sorted_src);

    // ---- bf16 gather table for layer 1 ----
    to_bf16<<<cvt_blocks, 256, 0, stream>>>(x, xb);

    // ---- layer 1 ----
    gather_mean<<<gather_blocks, 256, 0, stream>>>((const unsigned int*)xb,
                                                   row_ptr, sorted_src, meanb);
    sage_gemv<<<gemv_blocks, 256, 0, stream>>>(x, meanb, W1l, W1r, b1, h1, h1b);

    // ---- layer 2 ----
    gather_mean<<<gather_blocks, 256, 0, stream>>>((const unsigned int*)h1b,
                                                   row_ptr, sorted_src, meanb);
    sage_gemv<<<gemv_blocks, 256, 0, stream>>>(h1, meanb, W2l, W2r, b2,
                                               (float*)0, h2b);

    // ---- output projection ----
    out_layer<<<out_blocks, 256, 0, stream>>>((const unsigned int*)h2b, Wo, bo, out);
}

// Round 5
// 241.029 us; speedup vs baseline: 1.9515x; 1.3175x over previous
//
#include <hip/hip_runtime.h>

#define N_NODES 100000
#define N_EDGES 1000000
#define D 64
#define NCLS 10

#define NBUCK 196            // buckets of 512 nodes: bucket = dst >> 9
#define BNODES 512
#define P_BLOCKS 256         // partition blocks
#define P_EPB 3907           // edges per partition block; 256*3907 >= 1M

#define NPW 8                // nodes per wave in GEMV kernel
#define GEMV_WAVES 4
#define GEMV_NPB (NPW * GEMV_WAVES)   // 32 nodes per 256-thread block

// round-to-nearest-even f32 -> bf16 bits
__device__ __forceinline__ unsigned short f2bf(float x) {
    unsigned int u = __float_as_uint(x);
    u += 0x7fffu + ((u >> 16) & 1u);
    return (unsigned short)(u >> 16);
}
__device__ __forceinline__ unsigned int pack2bf(float lo, float hi) {
    return (unsigned int)f2bf(lo) | ((unsigned int)f2bf(hi) << 16);
}
__device__ __forceinline__ float bfsel(unsigned int wrd, int hi) {
    return __uint_as_float(hi ? (wrd & 0xffff0000u) : (wrd << 16));
}

// ---------------------------------------------------------------------------
// CSR build, bucketed counting sort. No global atomics, dense writes.
// ---------------------------------------------------------------------------
// Step 1: per-(block,bucket) histogram. histG[b * P_BLOCKS + blk].
__global__ __launch_bounds__(256) void edge_hist(const int* __restrict__ dst,
                                                 int* __restrict__ histG) {
    __shared__ int lh[256];
    const int tid = threadIdx.x;
    lh[tid] = 0;
    __syncthreads();
    const int e0 = blockIdx.x * P_EPB;
    int ecnt = N_EDGES - e0;
    if (ecnt > P_EPB) ecnt = P_EPB;
    if (ecnt < 0) ecnt = 0;
    for (int i = tid; i < ecnt; i += 256)
        atomicAdd(&lh[dst[e0 + i] >> 9], 1);   // LDS atomic
    __syncthreads();
    if (tid < NBUCK) histG[tid * P_BLOCKS + blockIdx.x] = lh[tid];
}

// Step 2a: per-256-chunk partial sums of histG (M = NBUCK*256 exactly).
__global__ __launch_bounds__(256) void scan_partials(const int* __restrict__ in,
                                                     int* __restrict__ blockSum) {
    __shared__ int s[256];
    s[threadIdx.x] = in[blockIdx.x * 256 + threadIdx.x];
    __syncthreads();
    for (int st = 128; st > 0; st >>= 1) {
        if (threadIdx.x < st) s[threadIdx.x] += s[threadIdx.x + st];
        __syncthreads();
    }
    if (threadIdx.x == 0) blockSum[blockIdx.x] = s[0];
}

// Step 2b: exclusive scan of the NBUCK partials (single block).
__global__ __launch_bounds__(256) void scan_offsets(const int* __restrict__ blockSum,
                                                    int* __restrict__ blockOff) {
    __shared__ int s[256];
    const int t = threadIdx.x;
    int v = (t < NBUCK) ? blockSum[t] : 0;
    s[t] = v;
    __syncthreads();
    for (int st = 1; st < 256; st <<= 1) {
        int u = (t >= st) ? s[t - st] : 0;
        __syncthreads();
        s[t] += u;
        __syncthreads();
    }
    if (t < NBUCK) blockOff[t] = s[t] - v;
}

// Step 2c: full exclusive scan -> ebase[NBUCK*P_BLOCKS].
__global__ __launch_bounds__(256) void scan_final(const int* __restrict__ in,
                                                  const int* __restrict__ blockOff,
                                                  int* __restrict__ ebase) {
    __shared__ int s[256];
    const int t = threadIdx.x;
    const int i = blockIdx.x * 256 + t;
    int v = in[i];
    s[t] = v;
    __syncthreads();
    for (int st = 1; st < 256; st <<= 1) {
        int u = (t >= st) ? s[t - st] : 0;
        __syncthreads();
        s[t] += u;
        __syncthreads();
    }
    ebase[i] = s[t] - v + blockOff[blockIdx.x];
}

// Step 3: partition edges into bucket-sorted pair array. Each block stages
// its edges bucket-contiguously in LDS, then emits coalesced runs.
__global__ __launch_bounds__(256) void edge_partition(const int* __restrict__ src,
                                                      const int* __restrict__ dst,
                                                      const int* __restrict__ ebase,
                                                      uint2* __restrict__ pairs) {
    __shared__ int s[256];
    __shared__ int lbase[256];
    __shared__ int lcur[256];
    __shared__ uint2 buf[P_EPB];
    const int tid = threadIdx.x;
    const int e0 = blockIdx.x * P_EPB;
    int ecnt = N_EDGES - e0;
    if (ecnt > P_EPB) ecnt = P_EPB;
    if (ecnt < 0) ecnt = 0;

    lcur[tid] = 0;
    __syncthreads();
    for (int i = tid; i < ecnt; i += 256)
        atomicAdd(&lcur[dst[e0 + i] >> 9], 1);
    __syncthreads();
    int v = lcur[tid];
    s[tid] = v;
    __syncthreads();
    for (int st = 1; st < 256; st <<= 1) {
        int u = (tid >= st) ? s[tid - st] : 0;
        __syncthreads();
        s[tid] += u;
        __syncthreads();
    }
    int excl = s[tid] - v;
    lbase[tid] = excl;
    lcur[tid] = excl;
    __syncthreads();
    for (int i = tid; i < ecnt; i += 256) {
        int d = dst[e0 + i], sv = src[e0 + i];
        int p = atomicAdd(&lcur[d >> 9], 1);
        buf[p] = make_uint2((unsigned)sv, (unsigned)d);
    }
    __syncthreads();
    for (int i = tid; i < ecnt; i += 256) {
        uint2 pr = buf[i];
        int bk = (int)(pr.y >> 9);
        pairs[ebase[bk * P_BLOCKS + blockIdx.x] + (i - lbase[bk])] = pr;
    }
}

// Step 4: per-bucket node counts + scan -> row_ptr; LDS-cursor scatter of
// src into sorted_src. One block owns one contiguous output region.
__global__ __launch_bounds__(256) void bucket_csr(const uint2* __restrict__ pairs,
                                                  const int* __restrict__ ebase,
                                                  int* __restrict__ row_ptr,
                                                  int* __restrict__ sorted_src) {
    __shared__ int h[BNODES];    // counts -> exclusive scan -> cursors
    __shared__ int part[256];
    const int tid = threadIdx.x;
    const int b = blockIdx.x;
    const int base = ebase[b * P_BLOCKS];
    const int next = (b == NBUCK - 1) ? N_EDGES : ebase[(b + 1) * P_BLOCKS];
    const int cnt = next - base;
    const int n0 = b * BNODES;

    h[tid] = 0; h[tid + 256] = 0;
    __syncthreads();
    for (int i = tid; i < cnt; i += 256)
        atomicAdd(&h[(int)pairs[base + i].y - n0], 1);
    __syncthreads();
    int a0 = h[2 * tid], a1 = h[2 * tid + 1];
    part[tid] = a0 + a1;
    __syncthreads();
    for (int st = 1; st < 256; st <<= 1) {
        int u = (tid >= st) ? part[tid - st] : 0;
        __syncthreads();
        part[tid] += u;
        __syncthreads();
    }
    int eb = part[tid] - (a0 + a1);          // exclusive base of node pair
    h[2 * tid] = eb;
    h[2 * tid + 1] = eb + a0;
    int node0 = n0 + 2 * tid;
    if (node0 <= N_NODES) row_ptr[node0] = base + eb;
    if (node0 + 1 <= N_NODES) row_ptr[node0 + 1] = base + eb + a0;
    __syncthreads();
    for (int i = tid; i < cnt; i += 256) {
        uint2 pr = pairs[base + i];
        int p = atomicAdd(&h[(int)pr.y - n0], 1);
        sorted_src[base + p] = (int)pr.x;
    }
}

// ---------------------------------------------------------------------------
// fp32 -> packed bf16 feature table (row = 64 ushorts = 32 dwords = 128B)
// ---------------------------------------------------------------------------
__global__ __launch_bounds__(256) void to_bf16(const float* __restrict__ in,
                                               unsigned short* __restrict__ out) {
    int i = blockIdx.x * 256 + threadIdx.x;   // float4 index
    if (i < N_NODES * D / 4) {
        float4 v = ((const float4*)in)[i];
        ushort4 o;
        o.x = f2bf(v.x); o.y = f2bf(v.y); o.z = f2bf(v.z); o.w = f2bf(v.w);
        ((ushort4*)out)[i] = o;
    }
}

// ---------------------------------------------------------------------------
// Gather kernel: mean over CSR neighbors, bf16 rows -> bf16 mean rows.
// Zero LDS, low VGPR -> max occupancy (latency-bound phase). One wave per
// node; lanes 0-31 = edge i, lanes 32-63 = edge i+1; 4 loads in flight.
// ---------------------------------------------------------------------------
__global__ __launch_bounds__(256) void gather_mean(
        const unsigned int* __restrict__ featb,   // bf16-packed [N][32]
        const int* __restrict__ row_ptr,
        const int* __restrict__ sorted_src,
        unsigned int* __restrict__ meanb) {       // bf16-packed [N][32]
    const int w  = threadIdx.x >> 6;
    const int f  = threadIdx.x & 63;
    const int h  = f >> 5;             // edge parity
    const int l5 = f & 31;             // dword within row
    const int node = blockIdx.x * 4 + w;
    if (node >= N_NODES) return;

    int start = row_ptr[node];
    int deg   = row_ptr[node + 1] - start;

    float a0 = 0.f, a1 = 0.f, a2 = 0.f, a3 = 0.f,
          a4 = 0.f, a5 = 0.f, a6 = 0.f, a7 = 0.f;
    for (int base = 0; base < deg; base += 64) {
        int nb = min(64, deg - base);
        int sl = (f < nb) ? sorted_src[start + base + f] : 0;
        int npairs = (nb + 1) >> 1;
        int t = 0;
        for (; t + 4 <= npairs; t += 4) {          // 8 edges, 4 loads in flight
            int iA = 2 * t + h, iB = iA + 2, iC = iA + 4, iD = iA + 6;
            int sA = __shfl(sl, iA), sB = __shfl(sl, iB);
            int sC = __shfl(sl, iC), sD = __shfl(sl, iD);
            unsigned int wA = (iA < nb) ? featb[sA * 32 + l5] : 0u;
            unsigned int wB = (iB < nb) ? featb[sB * 32 + l5] : 0u;
            unsigned int wC = (iC < nb) ? featb[sC * 32 + l5] : 0u;
            unsigned int wD = (iD < nb) ? featb[sD * 32 + l5] : 0u;
            a0 += __uint_as_float(wA << 16);
            a1 += __uint_as_float(wA & 0xffff0000u);
            a2 += __uint_as_float(wB << 16);
            a3 += __uint_as_float(wB & 0xffff0000u);
            a4 += __uint_as_float(wC << 16);
            a5 += __uint_as_float(wC & 0xffff0000u);
            a6 += __uint_as_float(wD << 16);
            a7 += __uint_as_float(wD & 0xffff0000u);
        }
        for (; t < npairs; ++t) {                  // tail pairs
            int iA = 2 * t + h;
            int sA = __shfl(sl, iA);
            unsigned int wA = (iA < nb) ? featb[sA * 32 + l5] : 0u;
            a0 += __uint_as_float(wA << 16);
            a1 += __uint_as_float(wA & 0xffff0000u);
        }
    }
    float b0 = (a0 + a2) + (a4 + a6);   // feature 2*l5
    float b1 = (a1 + a3) + (a5 + a7);   // feature 2*l5+1
    b0 += __shfl_xor(b0, 32);           // combine edge-parity halves
    b1 += __shfl_xor(b1, 32);
    float inv = 1.0f / fmaxf((float)deg, 1.0f);
    if (h == 0) meanb[node * 32 + l5] = pack2bf(b0 * inv, b1 * inv);
}

// ---------------------------------------------------------------------------
// Streaming fused GEMV: outb = bf16(relu(mean @ Wl^T + self @ Wr^T + b))
// Both inputs bf16-packed; weights fp32 in chunk-XOR-swizzled LDS
// (conflict-free ds_read_b128); each wave amortizes a weight read over
// 8 nodes. Streaming, BW-bound.
// ---------------------------------------------------------------------------
__global__ __launch_bounds__(256) void sage_gemv(
        const unsigned int* __restrict__ selfb,    // bf16-packed [N][32]
        const unsigned int* __restrict__ meanb,    // bf16-packed [N][32]
        const float* __restrict__ Wl,
        const float* __restrict__ Wr,
        const float* __restrict__ bias,
        unsigned short* __restrict__ outb) {       // bf16 [N][64]
    __shared__ __align__(16) float sWl[D * D];
    __shared__ __align__(16) float sWr[D * D];
    __shared__ __align__(16) float srow[GEMV_WAVES][NPW][2][D];

    for (int i = threadIdx.x; i < D * D / 4; i += 256) {
        int o = i >> 4;          // row
        int c = i & 15;          // logical chunk (4 floats)
        int pc = c ^ (o & 15);   // physical chunk
        *((float4*)&sWl[(o << 6) + (pc << 2)]) = ((const float4*)Wl)[i];
        *((float4*)&sWr[(o << 6) + (pc << 2)]) = ((const float4*)Wr)[i];
    }
    __syncthreads();

    const int w = threadIdx.x >> 6;
    const int f = threadIdx.x & 63;
    const int nodeBase = blockIdx.x * GEMV_NPB + w * NPW;
    const float bl = bias[f];

    // stage 8 nodes' self+mean rows (wave-private -> no block barrier)
#pragma unroll
    for (int r = 0; r < NPW; ++r) {
        int node = nodeBase + r;
        if (node >= N_NODES) break;
        unsigned int sw = selfb[node * 32 + (f >> 1)];
        unsigned int mw = meanb[node * 32 + (f >> 1)];
        srow[w][r][0][f] = bfsel(sw, f & 1);
        srow[w][r][1][f] = bfsel(mw, f & 1);
    }

    float acc[NPW];
#pragma unroll
    for (int r = 0; r < NPW; ++r) acc[r] = bl;

#pragma unroll 4
    for (int c = 0; c < 16; ++c) {
        const int wi = (f << 6) + ((c ^ (f & 15)) << 2);
        const float4 wl4 = *(const float4*)&sWl[wi];
        const float4 wr4 = *(const float4*)&sWr[wi];
#pragma unroll
        for (int r = 0; r < NPW; ++r) {
            const float4 m4 = *(const float4*)&srow[w][r][1][c << 2];
            const float4 s4 = *(const float4*)&srow[w][r][0][c << 2];
            float a = acc[r];
            a = fmaf(m4.x, wl4.x, a); a = fmaf(m4.y, wl4.y, a);
            a = fmaf(m4.z, wl4.z, a); a = fmaf(m4.w, wl4.w, a);
            a = fmaf(s4.x, wr4.x, a); a = fmaf(s4.y, wr4.y, a);
            a = fmaf(s4.z, wr4.z, a); a = fmaf(s4.w, wr4.w, a);
            acc[r] = a;
        }
    }

#pragma unroll
    for (int r = 0; r < NPW; ++r) {
        int node = nodeBase + r;
        if (node < N_NODES)
            outb[node * D + f] = f2bf(fmaxf(acc[r], 0.0f));
    }
}

// ---------------------------------------------------------------------------
// Output projection from bf16 h2: out = h @ W_out^T + b_out   [N, 10]
// ---------------------------------------------------------------------------
__global__ __launch_bounds__(256) void out_layer(const unsigned int* __restrict__ hb,
                                                 const float* __restrict__ Wout,
                                                 const float* __restrict__ bout,
                                                 float* __restrict__ out) {
    __shared__ float sW[NCLS][D + 1];
    __shared__ float sh[64][D + 1];

    for (int i = threadIdx.x; i < NCLS * D; i += 256) {
        sW[i / D][i % D] = Wout[i];
    }
    int n0 = blockIdx.x * 64;
    for (int i = threadIdx.x; i < 64 * 32; i += 256) {   // bf16 words
        int nl = i >> 5, kw = i & 31;
        int node = n0 + nl;
        unsigned int v = (node < N_NODES) ? hb[node * 32 + kw] : 0u;
        sh[nl][2 * kw]     = __uint_as_float(v << 16);
        sh[nl][2 * kw + 1] = __uint_as_float(v & 0xffff0000u);
    }
    __syncthreads();

    for (int oi = threadIdx.x; oi < 64 * NCLS; oi += 256) {
        int nl = oi / NCLS, c = oi % NCLS;
        int node = n0 + nl;
        if (node >= N_NODES) continue;
        float acc = bout[c];
#pragma unroll
        for (int k = 0; k < D; ++k) acc = fmaf(sh[nl][k], sW[c][k], acc);
        out[(long long)node * NCLS + c] = acc;
    }
}

// ---------------------------------------------------------------------------
extern "C" void kernel_launch(void* const* d_in, const int* in_sizes, int n_in,
                              void* d_out, int out_size, void* d_ws, size_t ws_size,
                              hipStream_t stream) {
    const float* x   = (const float*)d_in[0];
    const int*   ei  = (const int*)d_in[1];   // [2, N_EDGES]
    const int*   src = ei;
    const int*   dst = ei + N_EDGES;
    const float* W1l = (const float*)d_in[2];
    const float* W1r = (const float*)d_in[3];
    const float* b1  = (const float*)d_in[4];
    const float* W2l = (const float*)d_in[5];
    const float* W2r = (const float*)d_in[6];
    const float* b2  = (const float*)d_in[7];
    const float* Wo  = (const float*)d_in[8];
    const float* bo  = (const float*)d_in[9];
    float* out = (float*)d_out;

    char* ws = (char*)d_ws;
    int*   histG      = (int*)(ws + 0x0000000);  // 50176 ints (196*256) ~200KB
    int*   scanP      = (int*)(ws + 0x0040000);  // 196 ints
    int*   scanOff    = (int*)(ws + 0x0042000);  // 196 ints
    int*   ebase      = (int*)(ws + 0x0044000);  // 50176 ints ~200KB
    int*   row_ptr    = (int*)(ws + 0x0080000);  // 100001 ints ~400KB
    uint2* pairs      = (uint2*)(ws + 0x0100000);           // 8 MB
    int*   sorted_src = (int*)(ws + 0x0900000);             // 4 MB
    unsigned short* xb    = (unsigned short*)(ws + 0x0D00000); // 12.8 MB bf16
    unsigned int*   meanb = (unsigned int*)(ws + 0x1940000);   // 12.8 MB bf16
    unsigned short* h1b   = (unsigned short*)(ws + 0x2580000); // 12.8 MB bf16
    unsigned short* h2b   = (unsigned short*)(ws + 0x31C0000); // 12.8 MB bf16
    // total ~64.9 MB (within the ~70 MB envelope already in use)

    const int gather_blocks = (N_NODES + 3) / 4;                   // 25000
    const int gemv_blocks   = (N_NODES + GEMV_NPB - 1) / GEMV_NPB; // 3125
    const int out_blocks    = (N_NODES + 63) / 64;                 // 1563
    const int cvt_blocks    = (N_NODES * D / 4 + 255) / 256;

    // ---- CSR build: bucketed counting sort (no global atomics) ----
    edge_hist<<<P_BLOCKS, 256, 0, stream>>>(dst, histG);
    scan_partials<<<NBUCK, 256, 0, stream>>>(histG, scanP);
    scan_offsets<<<1, 256, 0, stream>>>(scanP, scanOff);
    scan_final<<<NBUCK, 256, 0, stream>>>(histG, scanOff, ebase);
    edge_partition<<<P_BLOCKS, 256, 0, stream>>>(src, dst, ebase, pairs);
    bucket_csr<<<NBUCK, 256, 0, stream>>>(pairs, ebase, row_ptr, sorted_src);

    // ---- bf16 feature table for layer 1 ----
    to_bf16<<<cvt_blocks, 256, 0, stream>>>(x, xb);

    // ---- layer 1 ----
    gather_mean<<<gather_blocks, 256, 0, stream>>>((const unsigned int*)xb,
                                                   row_ptr, sorted_src, meanb);
    sage_gemv<<<gemv_blocks, 256, 0, stream>>>((const unsigned int*)xb, meanb,
                                               W1l, W1r, b1, h1b);

    // ---- layer 2 ----
    gather_mean<<<gather_blocks, 256, 0, stream>>>((const unsigned int*)h1b,
                                                   row_ptr, sorted_src, meanb);
    sage_gemv<<<gemv_blocks, 256, 0, stream>>>((const unsigned int*)h1b, meanb,
                                               W2l, W2r, b2, h2b);

    // ---- output projection ----
    out_layer<<<out_blocks, 256, 0, stream>>>((const unsigned int*)h2b, Wo, bo, out);
}

// Round 6
// 154.159 us; speedup vs baseline: 3.0512x; 1.5635x over previous
//
#include <hip/hip_runtime.h>

#define N_NODES 100000
#define N_EDGES 1000000
#define D 64
#define NCLS 10
#define NTILES (N_NODES / 16)   // 6250, exact

#define NBUCK 196            // buckets of 512 nodes: bucket = dst >> 9
#define BNODES 512
#define P_BLOCKS 256         // partition blocks
#define P_EPB 3907           // edges per partition block; 256*3907 >= 1M

typedef __attribute__((ext_vector_type(8))) short bf16x8;   // 8 bf16 = 4 VGPR
typedef __attribute__((ext_vector_type(4))) float f32x4;

// round-to-nearest-even f32 -> bf16 bits
__device__ __forceinline__ unsigned short f2bf(float x) {
    unsigned int u = __float_as_uint(x);
    u += 0x7fffu + ((u >> 16) & 1u);
    return (unsigned short)(u >> 16);
}
__device__ __forceinline__ unsigned int pack2bf(float lo, float hi) {
    return (unsigned int)f2bf(lo) | ((unsigned int)f2bf(hi) << 16);
}

// ---------------------------------------------------------------------------
// CSR build, bucketed counting sort. No global atomics, dense writes.
// ---------------------------------------------------------------------------
__global__ __launch_bounds__(256) void edge_hist(const int* __restrict__ dst,
                                                 int* __restrict__ histG) {
    __shared__ int lh[256];
    const int tid = threadIdx.x;
    lh[tid] = 0;
    __syncthreads();
    const int e0 = blockIdx.x * P_EPB;
    int ecnt = N_EDGES - e0;
    if (ecnt > P_EPB) ecnt = P_EPB;
    if (ecnt < 0) ecnt = 0;
    for (int i = tid; i < ecnt; i += 256)
        atomicAdd(&lh[dst[e0 + i] >> 9], 1);   // LDS atomic
    __syncthreads();
    if (tid < NBUCK) histG[tid * P_BLOCKS + blockIdx.x] = lh[tid];
}

__global__ __launch_bounds__(256) void scan_partials(const int* __restrict__ in,
                                                     int* __restrict__ blockSum) {
    __shared__ int s[256];
    s[threadIdx.x] = in[blockIdx.x * 256 + threadIdx.x];
    __syncthreads();
    for (int st = 128; st > 0; st >>= 1) {
        if (threadIdx.x < st) s[threadIdx.x] += s[threadIdx.x + st];
        __syncthreads();
    }
    if (threadIdx.x == 0) blockSum[blockIdx.x] = s[0];
}

__global__ __launch_bounds__(256) void scan_offsets(const int* __restrict__ blockSum,
                                                    int* __restrict__ blockOff) {
    __shared__ int s[256];
    const int t = threadIdx.x;
    int v = (t < NBUCK) ? blockSum[t] : 0;
    s[t] = v;
    __syncthreads();
    for (int st = 1; st < 256; st <<= 1) {
        int u = (t >= st) ? s[t - st] : 0;
        __syncthreads();
        s[t] += u;
        __syncthreads();
    }
    if (t < NBUCK) blockOff[t] = s[t] - v;
}

__global__ __launch_bounds__(256) void scan_final(const int* __restrict__ in,
                                                  const int* __restrict__ blockOff,
                                                  int* __restrict__ ebase) {
    __shared__ int s[256];
    const int t = threadIdx.x;
    const int i = blockIdx.x * 256 + t;
    int v = in[i];
    s[t] = v;
    __syncthreads();
    for (int st = 1; st < 256; st <<= 1) {
        int u = (t >= st) ? s[t - st] : 0;
        __syncthreads();
        s[t] += u;
        __syncthreads();
    }
    ebase[i] = s[t] - v + blockOff[blockIdx.x];
}

__global__ __launch_bounds__(256) void edge_partition(const int* __restrict__ src,
                                                      const int* __restrict__ dst,
                                                      const int* __restrict__ ebase,
                                                      uint2* __restrict__ pairs) {
    __shared__ int s[256];
    __shared__ int lbase[256];
    __shared__ int lcur[256];
    __shared__ uint2 buf[P_EPB];
    const int tid = threadIdx.x;
    const int e0 = blockIdx.x * P_EPB;
    int ecnt = N_EDGES - e0;
    if (ecnt > P_EPB) ecnt = P_EPB;
    if (ecnt < 0) ecnt = 0;

    lcur[tid] = 0;
    __syncthreads();
    for (int i = tid; i < ecnt; i += 256)
        atomicAdd(&lcur[dst[e0 + i] >> 9], 1);
    __syncthreads();
    int v = lcur[tid];
    s[tid] = v;
    __syncthreads();
    for (int st = 1; st < 256; st <<= 1) {
        int u = (tid >= st) ? s[tid - st] : 0;
        __syncthreads();
        s[tid] += u;
        __syncthreads();
    }
    int excl = s[tid] - v;
    lbase[tid] = excl;
    lcur[tid] = excl;
    __syncthreads();
    for (int i = tid; i < ecnt; i += 256) {
        int d = dst[e0 + i], sv = src[e0 + i];
        int p = atomicAdd(&lcur[d >> 9], 1);
        buf[p] = make_uint2((unsigned)sv, (unsigned)d);
    }
    __syncthreads();
    for (int i = tid; i < ecnt; i += 256) {
        uint2 pr = buf[i];
        int bk = (int)(pr.y >> 9);
        pairs[ebase[bk * P_BLOCKS + blockIdx.x] + (i - lbase[bk])] = pr;
    }
}

__global__ __launch_bounds__(256) void bucket_csr(const uint2* __restrict__ pairs,
                                                  const int* __restrict__ ebase,
                                                  int* __restrict__ row_ptr,
                                                  int* __restrict__ sorted_src) {
    __shared__ int h[BNODES];    // counts -> exclusive scan -> cursors
    __shared__ int part[256];
    const int tid = threadIdx.x;
    const int b = blockIdx.x;
    const int base = ebase[b * P_BLOCKS];
    const int next = (b == NBUCK - 1) ? N_EDGES : ebase[(b + 1) * P_BLOCKS];
    const int cnt = next - base;
    const int n0 = b * BNODES;

    h[tid] = 0; h[tid + 256] = 0;
    __syncthreads();
    for (int i = tid; i < cnt; i += 256)
        atomicAdd(&h[(int)pairs[base + i].y - n0], 1);
    __syncthreads();
    int a0 = h[2 * tid], a1 = h[2 * tid + 1];
    part[tid] = a0 + a1;
    __syncthreads();
    for (int st = 1; st < 256; st <<= 1) {
        int u = (tid >= st) ? part[tid - st] : 0;
        __syncthreads();
        part[tid] += u;
        __syncthreads();
    }
    int eb = part[tid] - (a0 + a1);          // exclusive base of node pair
    h[2 * tid] = eb;
    h[2 * tid + 1] = eb + a0;
    int node0 = n0 + 2 * tid;
    if (node0 <= N_NODES) row_ptr[node0] = base + eb;
    if (node0 + 1 <= N_NODES) row_ptr[node0 + 1] = base + eb + a0;
    __syncthreads();
    for (int i = tid; i < cnt; i += 256) {
        uint2 pr = pairs[base + i];
        int p = atomicAdd(&h[(int)pr.y - n0], 1);
        sorted_src[base + p] = (int)pr.x;
    }
}

// ---------------------------------------------------------------------------
// fp32 -> packed bf16 feature table (row = 64 ushorts = 32 dwords = 128B)
// ---------------------------------------------------------------------------
__global__ __launch_bounds__(256) void to_bf16(const float* __restrict__ in,
                                               unsigned short* __restrict__ out) {
    int i = blockIdx.x * 256 + threadIdx.x;   // float4 index
    if (i < N_NODES * D / 4) {
        float4 v = ((const float4*)in)[i];
        ushort4 o;
        o.x = f2bf(v.x); o.y = f2bf(v.y); o.z = f2bf(v.z); o.w = f2bf(v.w);
        ((ushort4*)out)[i] = o;
    }
}

// ---------------------------------------------------------------------------
// Weight pre-pack into MFMA B-fragment layout, bf16.
// B = [Wl | Wr]^T as [K=128][64]. Frag (t,n): K-tile t (32), N-tile n (16).
// Lane l: col j = n*16 + (l&15); k = t*32 + (l>>4)*8 + 2r(+1).
// packedB[(((t*4+n)*64)+l)*4 + r] = pack(bf16(k), bf16(k+1)).
// ---------------------------------------------------------------------------
__global__ __launch_bounds__(256) void prep_weights(const float* __restrict__ Wl,
                                                    const float* __restrict__ Wr,
                                                    unsigned int* __restrict__ packedB) {
    int idx = blockIdx.x * 256 + threadIdx.x;   // 0..4095
    if (idx >= 4096) return;
    int r    = idx & 3;
    int lane = (idx >> 2) & 63;
    int n    = (idx >> 8) & 3;
    int t    = idx >> 10;
    int j  = n * 16 + (lane & 15);
    int k0 = t * 32 + ((lane >> 4) << 3) + 2 * r;   // even; k0,k0+1 same half
    float lo = (k0 < 64) ? Wl[j * 64 + k0] : Wr[j * 64 + (k0 - 64)];
    float hi = (k0 + 1 < 64) ? Wl[j * 64 + k0 + 1] : Wr[j * 64 + (k0 - 63)];
    packedB[idx] = pack2bf(lo, hi);
}

// Same packing for W_out [10][64]: K=64 (2 K-tiles), one N-tile, cols >=10 zero.
__global__ __launch_bounds__(256) void prep_out(const float* __restrict__ Wout,
                                                unsigned int* __restrict__ packedBo) {
    int idx = blockIdx.x * 256 + threadIdx.x;   // 0..511
    if (idx >= 512) return;
    int r    = idx & 3;
    int lane = (idx >> 2) & 63;
    int t    = idx >> 8;
    int j  = lane & 15;
    int k0 = t * 32 + ((lane >> 4) << 3) + 2 * r;
    float lo = (j < NCLS) ? Wout[j * 64 + k0] : 0.f;
    float hi = (j < NCLS) ? Wout[j * 64 + k0 + 1] : 0.f;
    packedBo[idx] = pack2bf(lo, hi);
}

// ---------------------------------------------------------------------------
// Gather kernel: mean over CSR neighbors, bf16 rows -> bf16 mean rows.
// Zero LDS, low VGPR -> max occupancy (latency-bound phase). One wave per
// node; lanes 0-31 = edge i, lanes 32-63 = edge i+1; 4 loads in flight.
// ---------------------------------------------------------------------------
__global__ __launch_bounds__(256) void gather_mean(
        const unsigned int* __restrict__ featb,   // bf16-packed [N][32]
        const int* __restrict__ row_ptr,
        const int* __restrict__ sorted_src,
        unsigned int* __restrict__ meanb) {       // bf16-packed [N][32]
    const int w  = threadIdx.x >> 6;
    const int f  = threadIdx.x & 63;
    const int h  = f >> 5;             // edge parity
    const int l5 = f & 31;             // dword within row
    const int node = blockIdx.x * 4 + w;
    if (node >= N_NODES) return;

    int start = row_ptr[node];
    int deg   = row_ptr[node + 1] - start;

    float a0 = 0.f, a1 = 0.f, a2 = 0.f, a3 = 0.f,
          a4 = 0.f, a5 = 0.f, a6 = 0.f, a7 = 0.f;
    for (int base = 0; base < deg; base += 64) {
        int nb = min(64, deg - base);
        int sl = (f < nb) ? sorted_src[start + base + f] : 0;
        int npairs = (nb + 1) >> 1;
        int t = 0;
        for (; t + 4 <= npairs; t += 4) {          // 8 edges, 4 loads in flight
            int iA = 2 * t + h, iB = iA + 2, iC = iA + 4, iD = iA + 6;
            int sA = __shfl(sl, iA), sB = __shfl(sl, iB);
            int sC = __shfl(sl, iC), sD = __shfl(sl, iD);
            unsigned int wA = (iA < nb) ? featb[sA * 32 + l5] : 0u;
            unsigned int wB = (iB < nb) ? featb[sB * 32 + l5] : 0u;
            unsigned int wC = (iC < nb) ? featb[sC * 32 + l5] : 0u;
            unsigned int wD = (iD < nb) ? featb[sD * 32 + l5] : 0u;
            a0 += __uint_as_float(wA << 16);
            a1 += __uint_as_float(wA & 0xffff0000u);
            a2 += __uint_as_float(wB << 16);
            a3 += __uint_as_float(wB & 0xffff0000u);
            a4 += __uint_as_float(wC << 16);
            a5 += __uint_as_float(wC & 0xffff0000u);
            a6 += __uint_as_float(wD << 16);
            a7 += __uint_as_float(wD & 0xffff0000u);
        }
        for (; t < npairs; ++t) {                  // tail pairs
            int iA = 2 * t + h;
            int sA = __shfl(sl, iA);
            unsigned int wA = (iA < nb) ? featb[sA * 32 + l5] : 0u;
            a0 += __uint_as_float(wA << 16);
            a1 += __uint_as_float(wA & 0xffff0000u);
        }
    }
    float b0 = (a0 + a2) + (a4 + a6);   // feature 2*l5
    float b1 = (a1 + a3) + (a5 + a7);   // feature 2*l5+1
    b0 += __shfl_xor(b0, 32);           // combine edge-parity halves
    b1 += __shfl_xor(b1, 32);
    float inv = 1.0f / fmaxf((float)deg, 1.0f);
    if (h == 0) meanb[node * 32 + l5] = pack2bf(b0 * inv, b1 * inv);
}

// ---------------------------------------------------------------------------
// MFMA SAGE layer: outb = bf16(relu([mean||self] @ [Wl|Wr]^T + b))
// One 16-node tile per wave; A-frag = one 16B contiguous load per K-tile
// (row = lane&15, k-chunk = (lane>>4)*8); B pre-packed; 16 MFMAs/tile.
// Zero LDS, no barriers. C/D: col = lane&15, row = (lane>>4)*4 + reg (m89).
// ---------------------------------------------------------------------------
__global__ __launch_bounds__(256) void sage_mfma(
        const unsigned int* __restrict__ selfb,    // bf16-packed [N][32]
        const unsigned int* __restrict__ meanb,    // bf16-packed [N][32]
        const unsigned int* __restrict__ packedB,  // 4096 dwords
        const float* __restrict__ bias,
        unsigned short* __restrict__ outb) {       // bf16 [N][64]
    const int wv = threadIdx.x >> 6;
    const int l  = threadIdx.x & 63;
    const int tile = blockIdx.x * 4 + wv;
    if (tile >= NTILES) return;
    const int col = l & 15;
    const int g   = l >> 4;
    const int anode = tile * 16 + col;

    bf16x8 bf[4][4];   // [K-tile][N-tile]
#pragma unroll
    for (int t = 0; t < 4; ++t)
#pragma unroll
        for (int n = 0; n < 4; ++n)
            bf[t][n] = *(const bf16x8*)(packedB + ((((t << 2) | n) * 64 + l) << 2));

    const unsigned int* mrow = meanb + anode * 32;
    const unsigned int* srw  = selfb + anode * 32;
    bf16x8 af0 = *(const bf16x8*)(mrow + (g << 2));        // K 0..31
    bf16x8 af1 = *(const bf16x8*)(mrow + 16 + (g << 2));   // K 32..63
    bf16x8 af2 = *(const bf16x8*)(srw + (g << 2));         // K 64..95
    bf16x8 af3 = *(const bf16x8*)(srw + 16 + (g << 2));    // K 96..127

    f32x4 acc[4];
#pragma unroll
    for (int n = 0; n < 4; ++n) {
        f32x4 a = {0.f, 0.f, 0.f, 0.f};
        a = __builtin_amdgcn_mfma_f32_16x16x32_bf16(af0, bf[0][n], a, 0, 0, 0);
        a = __builtin_amdgcn_mfma_f32_16x16x32_bf16(af1, bf[1][n], a, 0, 0, 0);
        a = __builtin_amdgcn_mfma_f32_16x16x32_bf16(af2, bf[2][n], a, 0, 0, 0);
        a = __builtin_amdgcn_mfma_f32_16x16x32_bf16(af3, bf[3][n], a, 0, 0, 0);
        acc[n] = a;
    }

#pragma unroll
    for (int n = 0; n < 4; ++n) {
        int j = (n << 4) | col;
        float bj = bias[j];
#pragma unroll
        for (int r = 0; r < 4; ++r) {
            int node = tile * 16 + (g << 2) + r;
            outb[node * 64 + j] = f2bf(fmaxf(acc[n][r] + bj, 0.f));
        }
    }
}

// ---------------------------------------------------------------------------
// MFMA output projection: out = h2 @ W_out^T + b_out  (fp32 [N][10])
// ---------------------------------------------------------------------------
__global__ __launch_bounds__(256) void out_mfma(
        const unsigned int* __restrict__ hb,        // bf16-packed [N][32]
        const unsigned int* __restrict__ packedBo,  // 512 dwords
        const float* __restrict__ bout,
        float* __restrict__ out) {
    const int wv = threadIdx.x >> 6;
    const int l  = threadIdx.x & 63;
    const int tile = blockIdx.x * 4 + wv;
    if (tile >= NTILES) return;
    const int col = l & 15;
    const int g   = l >> 4;
    const int anode = tile * 16 + col;

    bf16x8 b0 = *(const bf16x8*)(packedBo + (l << 2));
    bf16x8 b1 = *(const bf16x8*)(packedBo + ((64 + l) << 2));
    const unsigned int* hrow = hb + anode * 32;
    bf16x8 a0 = *(const bf16x8*)(hrow + (g << 2));
    bf16x8 a1 = *(const bf16x8*)(hrow + 16 + (g << 2));

    f32x4 acc = {0.f, 0.f, 0.f, 0.f};
    acc = __builtin_amdgcn_mfma_f32_16x16x32_bf16(a0, b0, acc, 0, 0, 0);
    acc = __builtin_amdgcn_mfma_f32_16x16x32_bf16(a1, b1, acc, 0, 0, 0);

    if (col < NCLS) {
        float bj = bout[col];
#pragma unroll
        for (int r = 0; r < 4; ++r) {
            int node = tile * 16 + (g << 2) + r;
            out[node * NCLS + col] = acc[r] + bj;
        }
    }
}

// ---------------------------------------------------------------------------
extern "C" void kernel_launch(void* const* d_in, const int* in_sizes, int n_in,
                              void* d_out, int out_size, void* d_ws, size_t ws_size,
                              hipStream_t stream) {
    const float* x   = (const float*)d_in[0];
    const int*   ei  = (const int*)d_in[1];   // [2, N_EDGES]
    const int*   src = ei;
    const int*   dst = ei + N_EDGES;
    const float* W1l = (const float*)d_in[2];
    const float* W1r = (const float*)d_in[3];
    const float* b1  = (const float*)d_in[4];
    const float* W2l = (const float*)d_in[5];
    const float* W2r = (const float*)d_in[6];
    const float* b2  = (const float*)d_in[7];
    const float* Wo  = (const float*)d_in[8];
    const float* bo  = (const float*)d_in[9];
    float* out = (float*)d_out;

    char* ws = (char*)d_ws;
    int*   histG      = (int*)(ws + 0x0000000);  // 50176 ints
    int*   scanP      = (int*)(ws + 0x0040000);  // 196 ints
    int*   scanOff    = (int*)(ws + 0x0042000);  // 196 ints
    int*   ebase      = (int*)(ws + 0x0044000);  // 50176 ints
    int*   row_ptr    = (int*)(ws + 0x0080000);  // 100001 ints
    uint2* pairs      = (uint2*)(ws + 0x0100000);              // 8 MB
    int*   sorted_src = (int*)(ws + 0x0900000);                // 4 MB
    unsigned short* xb    = (unsigned short*)(ws + 0x0D00000); // 12.8 MB bf16
    unsigned int*   meanb = (unsigned int*)(ws + 0x1940000);   // 12.8 MB bf16
    unsigned short* h1b   = (unsigned short*)(ws + 0x2580000); // 12.8 MB bf16
    unsigned short* h2b   = (unsigned short*)(ws + 0x31C0000); // 12.8 MB bf16
    unsigned int* packedB1 = (unsigned int*)(ws + 0x3E00000);  // 16 KB
    unsigned int* packedB2 = (unsigned int*)(ws + 0x3E04000);  // 16 KB
    unsigned int* packedBo = (unsigned int*)(ws + 0x3E08000);  // 2 KB

    const int gather_blocks = (N_NODES + 3) / 4;       // 25000
    const int mfma_blocks   = (NTILES + 3) / 4;        // 1563
    const int cvt_blocks    = (N_NODES * D / 4 + 255) / 256;

    // ---- CSR build: bucketed counting sort (no global atomics) ----
    edge_hist<<<P_BLOCKS, 256, 0, stream>>>(dst, histG);
    scan_partials<<<NBUCK, 256, 0, stream>>>(histG, scanP);
    scan_offsets<<<1, 256, 0, stream>>>(scanP, scanOff);
    scan_final<<<NBUCK, 256, 0, stream>>>(histG, scanOff, ebase);
    edge_partition<<<P_BLOCKS, 256, 0, stream>>>(src, dst, ebase, pairs);
    bucket_csr<<<NBUCK, 256, 0, stream>>>(pairs, ebase, row_ptr, sorted_src);

    // ---- weight pre-pack + bf16 feature table ----
    prep_weights<<<16, 256, 0, stream>>>(W1l, W1r, packedB1);
    prep_weights<<<16, 256, 0, stream>>>(W2l, W2r, packedB2);
    prep_out<<<2, 256, 0, stream>>>(Wo, packedBo);
    to_bf16<<<cvt_blocks, 256, 0, stream>>>(x, xb);

    // ---- layer 1 ----
    gather_mean<<<gather_blocks, 256, 0, stream>>>((const unsigned int*)xb,
                                                   row_ptr, sorted_src, meanb);
    sage_mfma<<<mfma_blocks, 256, 0, stream>>>((const unsigned int*)xb, meanb,
                                               packedB1, b1, h1b);

    // ---- layer 2 ----
    gather_mean<<<gather_blocks, 256, 0, stream>>>((const unsigned int*)h1b,
                                                   row_ptr, sorted_src, meanb);
    sage_mfma<<<mfma_blocks, 256, 0, stream>>>((const unsigned int*)h1b, meanb,
                                               packedB2, b2, h2b);

    // ---- output projection ----
    out_mfma<<<mfma_blocks, 256, 0, stream>>>((const unsigned int*)h2b,
                                              packedBo, bo, out);
}

// Round 7
// 135.226 us; speedup vs baseline: 3.4784x; 1.1400x over previous
//
#include <hip/hip_runtime.h>

#define N_NODES 100000
#define N_EDGES 1000000
#define D 64
#define NCLS 10
#define NTILES (N_NODES / 16)   // 6250, exact

#define NBUCK 196            // buckets of 512 nodes: bucket = dst >> 9
#define BNODES 512
#define P_BLOCKS 256         // partition blocks
#define P_EPB 3907           // edges per partition block; 256*3907 >= 1M

#define CVT_BLOCKS (N_NODES * D / 4 / 256)   // 6250, exact

typedef __attribute__((ext_vector_type(8))) short bf16x8;   // 8 bf16 = 4 VGPR
typedef __attribute__((ext_vector_type(4))) float f32x4;

// round-to-nearest-even f32 -> bf16 bits
__device__ __forceinline__ unsigned short f2bf(float x) {
    unsigned int u = __float_as_uint(x);
    u += 0x7fffu + ((u >> 16) & 1u);
    return (unsigned short)(u >> 16);
}
__device__ __forceinline__ unsigned int pack2bf(float lo, float hi) {
    return (unsigned int)f2bf(lo) | ((unsigned int)f2bf(hi) << 16);
}

// ---------------------------------------------------------------------------
// CSR build, bucketed counting sort. No global atomics, dense writes.
// Edge record packed: (src << 9) | (dst & 511)  -- src < 2^17, 26 bits total.
// ---------------------------------------------------------------------------
__global__ __launch_bounds__(256) void edge_hist(const int* __restrict__ dst,
                                                 int* __restrict__ histG) {
    __shared__ int lh[256];
    const int tid = threadIdx.x;
    lh[tid] = 0;
    __syncthreads();
    const int e0 = blockIdx.x * P_EPB;
    int ecnt = N_EDGES - e0;
    if (ecnt > P_EPB) ecnt = P_EPB;
    if (ecnt < 0) ecnt = 0;
    for (int i = tid; i < ecnt; i += 256)
        atomicAdd(&lh[dst[e0 + i] >> 9], 1);   // LDS atomic
    __syncthreads();
    if (tid < NBUCK) histG[tid * P_BLOCKS + blockIdx.x] = lh[tid];
}

__global__ __launch_bounds__(256) void scan_partials(const int* __restrict__ in,
                                                     int* __restrict__ blockSum) {
    __shared__ int s[256];
    s[threadIdx.x] = in[blockIdx.x * 256 + threadIdx.x];
    __syncthreads();
    for (int st = 128; st > 0; st >>= 1) {
        if (threadIdx.x < st) s[threadIdx.x] += s[threadIdx.x + st];
        __syncthreads();
    }
    if (threadIdx.x == 0) blockSum[blockIdx.x] = s[0];
}

__global__ __launch_bounds__(256) void scan_offsets(const int* __restrict__ blockSum,
                                                    int* __restrict__ blockOff) {
    __shared__ int s[256];
    const int t = threadIdx.x;
    int v = (t < NBUCK) ? blockSum[t] : 0;
    s[t] = v;
    __syncthreads();
    for (int st = 1; st < 256; st <<= 1) {
        int u = (t >= st) ? s[t - st] : 0;
        __syncthreads();
        s[t] += u;
        __syncthreads();
    }
    if (t < NBUCK) blockOff[t] = s[t] - v;
}

__global__ __launch_bounds__(256) void scan_final(const int* __restrict__ in,
                                                  const int* __restrict__ blockOff,
                                                  int* __restrict__ ebase) {
    __shared__ int s[256];
    const int t = threadIdx.x;
    const int i = blockIdx.x * 256 + t;
    int v = in[i];
    s[t] = v;
    __syncthreads();
    for (int st = 1; st < 256; st <<= 1) {
        int u = (t >= st) ? s[t - st] : 0;
        __syncthreads();
        s[t] += u;
        __syncthreads();
    }
    ebase[i] = s[t] - v + blockOff[blockIdx.x];
}

__global__ __launch_bounds__(256) void edge_partition(const int* __restrict__ src,
                                                      const int* __restrict__ dst,
                                                      const int* __restrict__ ebase,
                                                      unsigned int* __restrict__ pairs) {
    __shared__ int s[256];
    __shared__ int lbase[256];
    __shared__ int lcur[256];
    __shared__ unsigned int buf[P_EPB];
    const int tid = threadIdx.x;
    const int e0 = blockIdx.x * P_EPB;
    int ecnt = N_EDGES - e0;
    if (ecnt > P_EPB) ecnt = P_EPB;
    if (ecnt < 0) ecnt = 0;

    lcur[tid] = 0;
    __syncthreads();
    for (int i = tid; i < ecnt; i += 256)
        atomicAdd(&lcur[dst[e0 + i] >> 9], 1);
    __syncthreads();
    int v = lcur[tid];
    s[tid] = v;
    __syncthreads();
    for (int st = 1; st < 256; st <<= 1) {
        int u = (tid >= st) ? s[tid - st] : 0;
        __syncthreads();
        s[tid] += u;
        __syncthreads();
    }
    int excl = s[tid] - v;
    lbase[tid] = excl;
    lcur[tid] = excl;
    __syncthreads();
    for (int i = tid; i < ecnt; i += 256) {
        int d = dst[e0 + i], sv = src[e0 + i];
        int p = atomicAdd(&lcur[d >> 9], 1);
        buf[p] = ((unsigned)sv << 9) | ((unsigned)d & 511u);
    }
    __syncthreads();
    for (int i = tid; i < ecnt; i += 256) {
        unsigned int pr = buf[i];
        // recover bucket: need full dst; bucket boundaries align with lbase
        // ranges, so find bucket via lbase: instead store bucket implicitly --
        // i lies in [lbase[bk], lbase[bk]+count). Use binary search? Cheaper:
        // re-read dst is another 4MB. Store bucket in bits [26,34)? src<<9 uses
        // bits 9..25; dst&511 bits 0..8; bucket needs 8 bits -> doesn't fit.
        // Solution: walk via saved per-thread knowledge is complex; instead
        // recompute bucket from position using lbase table in LDS (196 entries,
        // monotone): linear search is too slow; use the fact that each thread
        // processed i strided -- simplest correct: binary search over lbase.
        int lo = 0, hi = 255;           // find last bk with lbase[bk] <= i
        while (lo < hi) {
            int mid = (lo + hi + 1) >> 1;
            if (lbase[mid] <= i) lo = mid; else hi = mid - 1;
        }
        int bk = lo;
        pairs[ebase[bk * P_BLOCKS + blockIdx.x] + (i - lbase[bk])] = pr;
    }
}

__global__ __launch_bounds__(256) void bucket_csr(const unsigned int* __restrict__ pairs,
                                                  const int* __restrict__ ebase,
                                                  int* __restrict__ row_ptr,
                                                  int* __restrict__ sorted_src) {
    __shared__ int h[BNODES];    // counts -> exclusive scan -> cursors
    __shared__ int part[256];
    const int tid = threadIdx.x;
    const int b = blockIdx.x;
    const int base = ebase[b * P_BLOCKS];
    const int next = (b == NBUCK - 1) ? N_EDGES : ebase[(b + 1) * P_BLOCKS];
    const int cnt = next - base;
    const int n0 = b * BNODES;

    h[tid] = 0; h[tid + 256] = 0;
    __syncthreads();
    for (int i = tid; i < cnt; i += 256)
        atomicAdd(&h[pairs[base + i] & 511u], 1);
    __syncthreads();
    int a0 = h[2 * tid], a1 = h[2 * tid + 1];
    part[tid] = a0 + a1;
    __syncthreads();
    for (int st = 1; st < 256; st <<= 1) {
        int u = (tid >= st) ? part[tid - st] : 0;
        __syncthreads();
        part[tid] += u;
        __syncthreads();
    }
    int eb = part[tid] - (a0 + a1);          // exclusive base of node pair
    h[2 * tid] = eb;
    h[2 * tid + 1] = eb + a0;
    int node0 = n0 + 2 * tid;
    if (node0 <= N_NODES) row_ptr[node0] = base + eb;
    if (node0 + 1 <= N_NODES) row_ptr[node0 + 1] = base + eb + a0;
    __syncthreads();
    for (int i = tid; i < cnt; i += 256) {
        unsigned int pr = pairs[base + i];
        int p = atomicAdd(&h[pr & 511u], 1);
        sorted_src[base + p] = (int)(pr >> 9);
    }
}

// ---------------------------------------------------------------------------
// Fused prep kernel: bf16 feature table + all 3 weight packs (1 launch).
// Weight B-fragment layout: B = [Wl | Wr]^T as [K=128][64]. Frag (t,n):
// lane l: col j = n*16 + (l&15); k = t*32 + (l>>4)*8 + 2r(+1).
// ---------------------------------------------------------------------------
__global__ __launch_bounds__(256) void prep_all(const float* __restrict__ x,
                                                const float* __restrict__ W1l,
                                                const float* __restrict__ W1r,
                                                const float* __restrict__ W2l,
                                                const float* __restrict__ W2r,
                                                const float* __restrict__ Wout,
                                                unsigned short* __restrict__ xb,
                                                unsigned int* __restrict__ pB1,
                                                unsigned int* __restrict__ pB2,
                                                unsigned int* __restrict__ pBo) {
    const int b = blockIdx.x;
    const int tid = threadIdx.x;
    if (b < CVT_BLOCKS) {                       // x -> bf16 table
        int i = b * 256 + tid;                  // float4 index, exact bound
        float4 v = ((const float4*)x)[i];
        ushort4 o;
        o.x = f2bf(v.x); o.y = f2bf(v.y); o.z = f2bf(v.z); o.w = f2bf(v.w);
        ((ushort4*)xb)[i] = o;
    } else if (b < CVT_BLOCKS + 32) {           // two SAGE weight packs
        int wsel = (b - CVT_BLOCKS) >> 4;
        const float* Wl = wsel ? W2l : W1l;
        const float* Wr = wsel ? W2r : W1r;
        unsigned int* pB = wsel ? pB2 : pB1;
        int idx = ((b - CVT_BLOCKS) & 15) * 256 + tid;   // 0..4095
        int r    = idx & 3;
        int lane = (idx >> 2) & 63;
        int n    = (idx >> 8) & 3;
        int t    = idx >> 10;
        int j  = n * 16 + (lane & 15);
        int k0 = t * 32 + ((lane >> 4) << 3) + 2 * r;
        float lo = (k0 < 64) ? Wl[j * 64 + k0] : Wr[j * 64 + (k0 - 64)];
        float hi = (k0 + 1 < 64) ? Wl[j * 64 + k0 + 1] : Wr[j * 64 + (k0 - 63)];
        pB[idx] = pack2bf(lo, hi);
    } else {                                    // W_out pack (512 entries)
        int idx = (b - CVT_BLOCKS - 32) * 256 + tid;
        if (idx < 512) {
            int r    = idx & 3;
            int lane = (idx >> 2) & 63;
            int t    = idx >> 8;
            int j  = lane & 15;
            int k0 = t * 32 + ((lane >> 4) << 3) + 2 * r;
            float lo = (j < NCLS) ? Wout[j * 64 + k0] : 0.f;
            float hi = (j < NCLS) ? Wout[j * 64 + k0 + 1] : 0.f;
            pBo[idx] = pack2bf(lo, hi);
        }
    }
}

// ---------------------------------------------------------------------------
// Gather kernel: mean over CSR neighbors, bf16 rows -> bf16 mean rows.
// TWO nodes per wave, load streams interleaved -> 8 independent loads in
// flight (latency-bound phase; MLP is the lever). Zero LDS, ~45 VGPR.
// bf16 row = 128B = 32 dwords: lanes 0-31 = edge i, lanes 32-63 = edge i+1.
// ---------------------------------------------------------------------------
__global__ __launch_bounds__(256) void gather_mean(
        const unsigned int* __restrict__ featb,   // bf16-packed [N][32]
        const int* __restrict__ row_ptr,
        const int* __restrict__ sorted_src,
        unsigned int* __restrict__ meanb) {       // bf16-packed [N][32]
    const int w  = threadIdx.x >> 6;
    const int f  = threadIdx.x & 63;
    const int h  = f >> 5;             // edge parity
    const int l5 = f & 31;             // dword within row
    const int nodeA = (blockIdx.x * 4 + w) * 2;   // N_NODES even -> nodeB valid
    if (nodeA >= N_NODES) return;
    const int nodeB = nodeA + 1;

    int rpA0 = row_ptr[nodeA];
    int rpA1 = row_ptr[nodeA + 1];
    int rpB1 = row_ptr[nodeA + 2];
    int degA = rpA1 - rpA0;
    int degB = rpB1 - rpA1;
    int maxdeg = max(degA, degB);

    float aA0 = 0.f, aA1 = 0.f, aA2 = 0.f, aA3 = 0.f,
          aA4 = 0.f, aA5 = 0.f, aA6 = 0.f, aA7 = 0.f;
    float aB0 = 0.f, aB1 = 0.f, aB2 = 0.f, aB3 = 0.f,
          aB4 = 0.f, aB5 = 0.f, aB6 = 0.f, aB7 = 0.f;

    for (int base = 0; base < maxdeg; base += 64) {
        int nbA = degA - base; nbA = (nbA > 64) ? 64 : nbA;
        int nbB = degB - base; nbB = (nbB > 64) ? 64 : nbB;
        int slA = (f < nbA) ? sorted_src[rpA0 + base + f] : 0;
        int slB = (f < nbB) ? sorted_src[rpA1 + base + f] : 0;
        int npA = (nbA + 1) >> 1;
        int npB = (nbB + 1) >> 1;
        int np = max(npA, npB);
        for (int t = 0; t < np; t += 4) {          // 8 loads (16 edges) in flight
            int i0 = 2 * t + h, i1 = i0 + 2, i2 = i0 + 4, i3 = i0 + 6;
            int sA0 = __shfl(slA, i0), sA1 = __shfl(slA, i1);
            int sA2 = __shfl(slA, i2), sA3 = __shfl(slA, i3);
            int sB0 = __shfl(slB, i0), sB1 = __shfl(slB, i1);
            int sB2 = __shfl(slB, i2), sB3 = __shfl(slB, i3);
            unsigned int wA0 = (i0 < nbA) ? featb[sA0 * 32 + l5] : 0u;
            unsigned int wA1 = (i1 < nbA) ? featb[sA1 * 32 + l5] : 0u;
            unsigned int wA2 = (i2 < nbA) ? featb[sA2 * 32 + l5] : 0u;
            unsigned int wA3 = (i3 < nbA) ? featb[sA3 * 32 + l5] : 0u;
            unsigned int wB0 = (i0 < nbB) ? featb[sB0 * 32 + l5] : 0u;
            unsigned int wB1 = (i1 < nbB) ? featb[sB1 * 32 + l5] : 0u;
            unsigned int wB2 = (i2 < nbB) ? featb[sB2 * 32 + l5] : 0u;
            unsigned int wB3 = (i3 < nbB) ? featb[sB3 * 32 + l5] : 0u;
            aA0 += __uint_as_float(wA0 << 16);
            aA1 += __uint_as_float(wA0 & 0xffff0000u);
            aA2 += __uint_as_float(wA1 << 16);
            aA3 += __uint_as_float(wA1 & 0xffff0000u);
            aA4 += __uint_as_float(wA2 << 16);
            aA5 += __uint_as_float(wA2 & 0xffff0000u);
            aA6 += __uint_as_float(wA3 << 16);
            aA7 += __uint_as_float(wA3 & 0xffff0000u);
            aB0 += __uint_as_float(wB0 << 16);
            aB1 += __uint_as_float(wB0 & 0xffff0000u);
            aB2 += __uint_as_float(wB1 << 16);
            aB3 += __uint_as_float(wB1 & 0xffff0000u);
            aB4 += __uint_as_float(wB2 << 16);
            aB5 += __uint_as_float(wB2 & 0xffff0000u);
            aB6 += __uint_as_float(wB3 << 16);
            aB7 += __uint_as_float(wB3 & 0xffff0000u);
        }
    }
    float bA0 = (aA0 + aA2) + (aA4 + aA6);
    float bA1 = (aA1 + aA3) + (aA5 + aA7);
    float bB0 = (aB0 + aB2) + (aB4 + aB6);
    float bB1 = (aB1 + aB3) + (aB5 + aB7);
    bA0 += __shfl_xor(bA0, 32);   // combine edge-parity halves
    bA1 += __shfl_xor(bA1, 32);
    bB0 += __shfl_xor(bB0, 32);
    bB1 += __shfl_xor(bB1, 32);
    float invA = 1.0f / fmaxf((float)degA, 1.0f);
    float invB = 1.0f / fmaxf((float)degB, 1.0f);
    if (h == 0) meanb[nodeA * 32 + l5] = pack2bf(bA0 * invA, bA1 * invA);
    else        meanb[nodeB * 32 + l5] = pack2bf(bB0 * invB, bB1 * invB);
}

// ---------------------------------------------------------------------------
// MFMA SAGE layer: outb = bf16(relu([mean||self] @ [Wl|Wr]^T + b))
// One 16-node tile per wave; A-frag = one 16B contiguous load per K-tile
// (row = lane&15, k-chunk = (lane>>4)*8); B pre-packed; 16 MFMAs/tile.
// Zero LDS, no barriers. C/D: col = lane&15, row = (lane>>4)*4 + reg (m89).
// ---------------------------------------------------------------------------
__global__ __launch_bounds__(256) void sage_mfma(
        const unsigned int* __restrict__ selfb,    // bf16-packed [N][32]
        const unsigned int* __restrict__ meanb,    // bf16-packed [N][32]
        const unsigned int* __restrict__ packedB,  // 4096 dwords
        const float* __restrict__ bias,
        unsigned short* __restrict__ outb) {       // bf16 [N][64]
    const int wv = threadIdx.x >> 6;
    const int l  = threadIdx.x & 63;
    const int tile = blockIdx.x * 4 + wv;
    if (tile >= NTILES) return;
    const int col = l & 15;
    const int g   = l >> 4;
    const int anode = tile * 16 + col;

    bf16x8 bf[4][4];   // [K-tile][N-tile]
#pragma unroll
    for (int t = 0; t < 4; ++t)
#pragma unroll
        for (int n = 0; n < 4; ++n)
            bf[t][n] = *(const bf16x8*)(packedB + ((((t << 2) | n) * 64 + l) << 2));

    const unsigned int* mrow = meanb + anode * 32;
    const unsigned int* srw  = selfb + anode * 32;
    bf16x8 af0 = *(const bf16x8*)(mrow + (g << 2));        // K 0..31
    bf16x8 af1 = *(const bf16x8*)(mrow + 16 + (g << 2));   // K 32..63
    bf16x8 af2 = *(const bf16x8*)(srw + (g << 2));         // K 64..95
    bf16x8 af3 = *(const bf16x8*)(srw + 16 + (g << 2));    // K 96..127

    f32x4 acc[4];
#pragma unroll
    for (int n = 0; n < 4; ++n) {
        f32x4 a = {0.f, 0.f, 0.f, 0.f};
        a = __builtin_amdgcn_mfma_f32_16x16x32_bf16(af0, bf[0][n], a, 0, 0, 0);
        a = __builtin_amdgcn_mfma_f32_16x16x32_bf16(af1, bf[1][n], a, 0, 0, 0);
        a = __builtin_amdgcn_mfma_f32_16x16x32_bf16(af2, bf[2][n], a, 0, 0, 0);
        a = __builtin_amdgcn_mfma_f32_16x16x32_bf16(af3, bf[3][n], a, 0, 0, 0);
        acc[n] = a;
    }

#pragma unroll
    for (int n = 0; n < 4; ++n) {
        int j = (n << 4) | col;
        float bj = bias[j];
#pragma unroll
        for (int r = 0; r < 4; ++r) {
            int node = tile * 16 + (g << 2) + r;
            outb[node * 64 + j] = f2bf(fmaxf(acc[n][r] + bj, 0.f));
        }
    }
}

// ---------------------------------------------------------------------------
// MFMA output projection: out = h2 @ W_out^T + b_out  (fp32 [N][10])
// ---------------------------------------------------------------------------
__global__ __launch_bounds__(256) void out_mfma(
        const unsigned int* __restrict__ hb,        // bf16-packed [N][32]
        const unsigned int* __restrict__ packedBo,  // 512 dwords
        const float* __restrict__ bout,
        float* __restrict__ out) {
    const int wv = threadIdx.x >> 6;
    const int l  = threadIdx.x & 63;
    const int tile = blockIdx.x * 4 + wv;
    if (tile >= NTILES) return;
    const int col = l & 15;
    const int g   = l >> 4;
    const int anode = tile * 16 + col;

    bf16x8 b0 = *(const bf16x8*)(packedBo + (l << 2));
    bf16x8 b1 = *(const bf16x8*)(packedBo + ((64 + l) << 2));
    const unsigned int* hrow = hb + anode * 32;
    bf16x8 a0 = *(const bf16x8*)(hrow + (g << 2));
    bf16x8 a1 = *(const bf16x8*)(hrow + 16 + (g << 2));

    f32x4 acc = {0.f, 0.f, 0.f, 0.f};
    acc = __builtin_amdgcn_mfma_f32_16x16x32_bf16(a0, b0, acc, 0, 0, 0);
    acc = __builtin_amdgcn_mfma_f32_16x16x32_bf16(a1, b1, acc, 0, 0, 0);

    if (col < NCLS) {
        float bj = bout[col];
#pragma unroll
        for (int r = 0; r < 4; ++r) {
            int node = tile * 16 + (g << 2) + r;
            out[node * NCLS + col] = acc[r] + bj;
        }
    }
}

// ---------------------------------------------------------------------------
extern "C" void kernel_launch(void* const* d_in, const int* in_sizes, int n_in,
                              void* d_out, int out_size, void* d_ws, size_t ws_size,
                              hipStream_t stream) {
    const float* x   = (const float*)d_in[0];
    const int*   ei  = (const int*)d_in[1];   // [2, N_EDGES]
    const int*   src = ei;
    const int*   dst = ei + N_EDGES;
    const float* W1l = (const float*)d_in[2];
    const float* W1r = (const float*)d_in[3];
    const float* b1  = (const float*)d_in[4];
    const float* W2l = (const float*)d_in[5];
    const float* W2r = (const float*)d_in[6];
    const float* b2  = (const float*)d_in[7];
    const float* Wo  = (const float*)d_in[8];
    const float* bo  = (const float*)d_in[9];
    float* out = (float*)d_out;

    char* ws = (char*)d_ws;
    int*   histG      = (int*)(ws + 0x0000000);  // 50176 ints
    int*   scanP      = (int*)(ws + 0x0040000);  // 196 ints
    int*   scanOff    = (int*)(ws + 0x0042000);  // 196 ints
    int*   ebase      = (int*)(ws + 0x0044000);  // 50176 ints
    int*   row_ptr    = (int*)(ws + 0x0080000);  // 100001 ints
    unsigned int* pairs = (unsigned int*)(ws + 0x0100000);     // 4 MB (packed)
    int*   sorted_src = (int*)(ws + 0x0500000);                // 4 MB
    unsigned short* xb    = (unsigned short*)(ws + 0x0900000); // 12.8 MB bf16
    unsigned int*   meanb = (unsigned int*)(ws + 0x1540000);   // 12.8 MB bf16
    unsigned short* h1b   = (unsigned short*)(ws + 0x2180000); // 12.8 MB bf16
    unsigned short* h2b   = (unsigned short*)(ws + 0x2DC0000); // 12.8 MB bf16
    unsigned int* packedB1 = (unsigned int*)(ws + 0x3A00000);  // 16 KB
    unsigned int* packedB2 = (unsigned int*)(ws + 0x3A04000);  // 16 KB
    unsigned int* packedBo = (unsigned int*)(ws + 0x3A08000);  // 2 KB

    const int gather_blocks = (N_NODES / 2 + 3) / 4;   // 12500 (2 nodes/wave)
    const int mfma_blocks   = (NTILES + 3) / 4;        // 1563
    const int prep_blocks   = CVT_BLOCKS + 32 + 2;     // 6284

    // ---- CSR build: bucketed counting sort (no global atomics) ----
    edge_hist<<<P_BLOCKS, 256, 0, stream>>>(dst, histG);
    scan_partials<<<NBUCK, 256, 0, stream>>>(histG, scanP);
    scan_offsets<<<1, 256, 0, stream>>>(scanP, scanOff);
    scan_final<<<NBUCK, 256, 0, stream>>>(histG, scanOff, ebase);
    edge_partition<<<P_BLOCKS, 256, 0, stream>>>(src, dst, ebase, pairs);
    bucket_csr<<<NBUCK, 256, 0, stream>>>(pairs, ebase, row_ptr, sorted_src);

    // ---- fused prep: bf16 table + weight packs (1 launch) ----
    prep_all<<<prep_blocks, 256, 0, stream>>>(x, W1l, W1r, W2l, W2r, Wo,
                                              xb, packedB1, packedB2, packedBo);

    // ---- layer 1 ----
    gather_mean<<<gather_blocks, 256, 0, stream>>>((const unsigned int*)xb,
                                                   row_ptr, sorted_src, meanb);
    sage_mfma<<<mfma_blocks, 256, 0, stream>>>((const unsigned int*)xb, meanb,
                                               packedB1, b1, h1b);

    // ---- layer 2 ----
    gather_mean<<<gather_blocks, 256, 0, stream>>>((const unsigned int*)h1b,
                                                   row_ptr, sorted_src, meanb);
    sage_mfma<<<mfma_blocks, 256, 0, stream>>>((const unsigned int*)h1b, meanb,
                                               packedB2, b2, h2b);

    // ---- output projection ----
    out_mfma<<<mfma_blocks, 256, 0, stream>>>((const unsigned int*)h2b,
                                              packedBo, bo, out);
}